// Round 6
// baseline (560.941 us; speedup 1.0000x reference)
//
#include <hip/hip_runtime.h>

#define B_ 128
#define M_ 64
#define N_ 128
#define D_ 10
#define K_ 4
#define H_ 64
#define DT_ (1.0f/128.0f)
#define STRIKE_ 0.4f

// tanh(x) = (1 - e^{-2x}) / (1 + e^{-2x});  e^{-2x} = exp2(-2*log2(e)*x)
__device__ __forceinline__ float fast_tanh(float x) {
    x = fminf(30.f, fmaxf(-30.f, x));
    float e = __builtin_amdgcn_exp2f(x * -2.885390081777927f);
    return (1.f - e) * __builtin_amdgcn_rcpf(1.f + e);
}

// Setup: zero accumulators, build W1T[h][d] = W1[(1+d)*H + h] (the 10 x-rows, padded to 16)
extern "C" __global__ void solver_setup(const float* __restrict__ W1,
                                        float* __restrict__ W1T,
                                        float* gI, float* gT) {
    int h = threadIdx.x;
    if (h == 0) { *gI = 0.f; *gT = 0.f; }
    #pragma unroll
    for (int d = 0; d < 16; ++d)
        W1T[h * 16 + d] = (d < D_) ? W1[(1 + d) * H_ + h] : 0.f;
}

// launch_bounds(128,2): proven spill-free at ~88 VGPR (round 2). (128,4) forced
// VGPR=64 -> acc[64] spilled to scratch -> 123MB/dispatch HBM writes (round 4).
// HW can still run 4 waves/SIMD as long as actual VGPR <= 128.
extern "C" __global__ void __launch_bounds__(128, 2)
solver_main(const float* __restrict__ tt, const float* __restrict__ xx,
            const float* __restrict__ dw, const float* __restrict__ uu,
            const float* __restrict__ W1, const float* __restrict__ b1,
            const float* __restrict__ W2, const float* __restrict__ b2,
            const float* __restrict__ W3, const float* __restrict__ b3,
            const float* __restrict__ W1T,
            float* __restrict__ gI, float* __restrict__ gT)
{
    // h1 transposed, fp16: A1[h*128 + tid]. Per-thread column only -> no barrier.
    // h1 in (-1,1): fp16 abs err <= 2^-11; lanes stride 2B -> 2-way bank alias (free).
    __shared__ _Float16 A1[H_ * 128];
    __shared__ float payLDS;
    __shared__ float wtotLDS;
    __shared__ float wsum[2];

    const int bm = blockIdx.x;
    const int n  = threadIdx.x;          // time index along the path
    const int p  = bm * N_ + n;          // flat point index

    // ---- loads (all per-lane; consecutive lanes -> consecutive addresses) ----
    float tval = tt[p];
    float xr[D_];
    {
        const float2* v = reinterpret_cast<const float2*>(xx + (size_t)p * D_);
        #pragma unroll
        for (int i = 0; i < 5; ++i) { float2 w = v[i]; xr[2*i] = w.x; xr[2*i+1] = w.y; }
    }
    float4 uv = *reinterpret_cast<const float4*>(uu + (size_t)p * K_);
    float dwr[D_];
    if (n < N_ - 1) {
        const float2* v = reinterpret_cast<const float2*>(dw + ((size_t)bm * (N_-1) + n) * D_);
        #pragma unroll
        for (int i = 0; i < 5; ++i) { float2 w = v[i]; dwr[2*i] = w.x; dwr[2*i+1] = w.y; }
    } else {
        #pragma unroll
        for (int i = 0; i < D_; ++i) dwr[i] = 0.f;
    }
    float r_ = uv.x, sigma = uv.y;
    float a[D_];
    #pragma unroll
    for (int d = 0; d < D_; ++d) a[d] = sigma * xr[d] * dwr[d];

    // payoff from the terminal point (thread 127)
    if (n == N_ - 1) {
        float s = 0.f;
        #pragma unroll
        for (int d = 0; d < D_; ++d) s += xr[d];
        payLDS = fmaxf(s * (1.f / D_) - STRIKE_, 0.f);
    }

    // ---- layer 1: acc[h] = b1[h] + z . W1[:,h]   (W1 rows are wave-uniform -> s_load) ----
    float acc[H_];
    #pragma unroll
    for (int h = 0; h < H_; ++h) acc[h] = b1[h];
    #pragma unroll
    for (int h = 0; h < H_; ++h) acc[h] = fmaf(tval, W1[h], acc[h]);
    #pragma unroll
    for (int i = 0; i < D_; ++i) {
        const float* w = W1 + (1 + i) * H_;
        float zi = xr[i];
        #pragma unroll
        for (int h = 0; h < H_; ++h) acc[h] = fmaf(zi, w[h], acc[h]);
    }
    {
        float ur[K_] = {uv.x, uv.y, uv.z, uv.w};
        #pragma unroll
        for (int i = 0; i < K_; ++i) {
            const float* w = W1 + (1 + D_ + i) * H_;
            #pragma unroll
            for (int h = 0; h < H_; ++h) acc[h] = fmaf(ur[i], w[h], acc[h]);
        }
    }

    // h1 -> LDS fp16 (own column; no barrier needed, same-thread readback only)
    #pragma unroll
    for (int h = 0; h < H_; ++h) A1[h * 128 + n] = (_Float16)fast_tanh(acc[h]);

    // ---- layer 2: acc[h] = b2[h] + sum_i h1[i] * W2[i][h] ----
    #pragma unroll
    for (int h = 0; h < H_; ++h) acc[h] = b2[h];
    #pragma unroll 1
    for (int i = 0; i < H_; ++i) {
        float h1i = (float)A1[i * 128 + n];
        const float* w = W2 + i * H_;
        #pragma unroll
        for (int h = 0; h < H_; ++h) acc[h] = fmaf(h1i, w[h], acc[h]);
    }

    // ---- epilogue: f = b3 + W3 . tanh(acc);  g2[h] = W3[h]*(1-h2^2) kept in acc ----
    float fp[8];
    #pragma unroll
    for (int j = 0; j < 8; ++j) fp[j] = 0.f;
    #pragma unroll
    for (int h = 0; h < H_; ++h) {
        float h2 = fast_tanh(acc[h]);
        float w3 = W3[h];
        fp[h & 7] = fmaf(w3, h2, fp[h & 7]);
        acc[h] = w3 * (1.f - h2 * h2);
    }
    float f = ((fp[0]+fp[4]) + (fp[1]+fp[5])) + ((fp[2]+fp[6]) + (fp[3]+fp[7]));
    f += b3[0];

    // ---- backward + z-term:  zterm = sum_i g1_i * q_i ----
    // g1_i = (W2[i][:] . g2) * (1 - h1_i^2),  q_i = sum_d a_d * W1T[i][d]
    float zt[4]; zt[0] = zt[1] = zt[2] = zt[3] = 0.f;
    #pragma unroll 1
    for (int i = 0; i < H_; ++i) {
        const float* w = W2 + i * H_;
        float pp[8];
        #pragma unroll
        for (int j = 0; j < 8; ++j) pp[j] = 0.f;
        #pragma unroll
        for (int h = 0; h < H_; ++h) pp[h & 7] = fmaf(w[h], acc[h], pp[h & 7]);
        float gpre = ((pp[0]+pp[4]) + (pp[1]+pp[5])) + ((pp[2]+pp[6]) + (pp[3]+pp[7]));
        float h1i = (float)A1[i * 128 + n];
        float g1 = gpre * (1.f - h1i * h1i);
        const float* wt = W1T + i * 16;
        float q = 0.f;
        #pragma unroll
        for (int d = 0; d < D_; ++d) q = fmaf(a[d], wt[d], q);
        zt[i & 3] = fmaf(g1, q, zt[i & 3]);
    }
    float zterm = (zt[0] + zt[2]) + (zt[1] + zt[3]);

    // c[n] = r*f*DT - z  (0 at terminal)
    float cn = (n < N_ - 1) ? fmaf(r_ * f, DT_, -zterm) : 0.f;

    // ---- suffix scan S[n] = sum_{j>=n} c[j] over 128 threads (2 waves) ----
    float S = cn;
    #pragma unroll
    for (int off = 1; off < 64; off <<= 1) {
        float o = __shfl_down(S, off);
        S += (((n & 63) + off) < 64) ? o : 0.f;
    }
    if (n == 64) wtotLDS = S;          // total of wave 1 = sum_{64..127}
    __syncthreads();                   // also publishes payLDS
    if (n < 64) S += wtotLDS;
    float pay = payLDS;

    float resid = (n < N_ - 1) ? (pay - f + S) : 0.f;
    float v = resid * resid;
    #pragma unroll
    for (int off = 32; off; off >>= 1) v += __shfl_down(v, off);
    if ((n & 63) == 0) wsum[n >> 6] = v;
    __syncthreads();
    if (n == 0) atomicAdd(gI, wsum[0] + wsum[1]);
    if (n == N_ - 1) { float d0 = f - pay; atomicAdd(gT, d0 * d0); }
}

extern "C" __global__ void solver_fin(const float* gI, const float* gT, float* out) {
    float li = *gI * (1.f / (B_ * M_));
    float lt = *gT * (1.f / (B_ * M_));
    out[0] = 1.0f * lt + li;   // ALPHA = 1
    out[1] = li;
    out[2] = lt;
}

extern "C" void kernel_launch(void* const* d_in, const int* in_sizes, int n_in,
                              void* d_out, int out_size, void* d_ws, size_t ws_size,
                              hipStream_t stream) {
    const float* tt = (const float*)d_in[0];
    const float* xx = (const float*)d_in[1];
    const float* dw = (const float*)d_in[2];
    const float* uu = (const float*)d_in[3];
    const float* W1 = (const float*)d_in[4];
    const float* b1 = (const float*)d_in[5];
    const float* W2 = (const float*)d_in[6];
    const float* b2 = (const float*)d_in[7];
    const float* W3 = (const float*)d_in[8];
    const float* b3 = (const float*)d_in[9];
    float* out = (float*)d_out;
    float* ws  = (float*)d_ws;
    float* gI  = ws;          // [0] interior sum
    float* gT  = ws + 1;      // [1] terminal sum
    float* W1T = ws + 8;      // 64*16 floats, 32B-aligned

    hipLaunchKernelGGL(solver_setup, dim3(1), dim3(64), 0, stream, W1, W1T, gI, gT);
    hipLaunchKernelGGL(solver_main, dim3(B_ * M_), dim3(N_), 0, stream,
                       tt, xx, dw, uu, W1, b1, W2, b2, W3, b3, W1T, gI, gT);
    hipLaunchKernelGGL(solver_fin, dim3(1), dim3(1), 0, stream, gI, gT, out);
}

// Round 10
// 501.587 us; speedup vs baseline: 1.1183x; 1.1183x over previous
//
#include <hip/hip_runtime.h>

#define B_ 128
#define M_ 64
#define N_ 128
#define D_ 10
#define K_ 4
#define H_ 64
#define DT_ (1.0f/128.0f)
#define STRIKE_ 0.4f

// tanh(x) = (1 - e^{-2x}) / (1 + e^{-2x});  e^{-2x} = exp2(-2*log2(e)*x)
__device__ __forceinline__ float fast_tanh(float x) {
    x = fminf(30.f, fmaxf(-30.f, x));
    float e = __builtin_amdgcn_exp2f(x * -2.885390081777927f);
    return (1.f - e) * __builtin_amdgcn_rcpf(1.f + e);
}

// Setup: zero accumulators, build W1T[h][d] = W1[(1+d)*H + h] (the 10 x-rows, padded to 16)
extern "C" __global__ void solver_setup(const float* __restrict__ W1,
                                        float* __restrict__ W1T,
                                        float* gI, float* gT) {
    int h = threadIdx.x;
    if (h == 0) { *gI = 0.f; *gT = 0.f; }
    #pragma unroll
    for (int d = 0; d < 16; ++d)
        W1T[h * 16 + d] = (d < D_) ? W1[(1 + d) * H_ + h] : 0.f;
}

// 256-thread blocks = 2 paths/block. R6 showed residency stuck at ~4.7 blocks/CU
// (9.5 waves) despite LDS cap of 9 blocks -> suspect per-CU WG-slot packing limit.
// 4 waves per WG slot: 4 blocks/CU x 4 waves = 16 waves/CU under the LDS cap.
// lb(256,2): VGPR cap 256, allocator uses ~80 (proven spill-free per-thread code).
extern "C" __global__ void __launch_bounds__(256, 2)
solver_main(const float* __restrict__ tt, const float* __restrict__ xx,
            const float* __restrict__ dw, const float* __restrict__ uu,
            const float* __restrict__ W1, const float* __restrict__ b1,
            const float* __restrict__ W2, const float* __restrict__ b2,
            const float* __restrict__ W3, const float* __restrict__ b3,
            const float* __restrict__ W1T,
            float* __restrict__ gI, float* __restrict__ gT)
{
    // h1 transposed, fp16: A1[h*256 + tid]. Per-thread column only -> no barrier.
    // h1 in (-1,1): fp16 abs err <= 2^-11; lanes stride 2B -> 2-way bank alias (free).
    __shared__ _Float16 A1[H_ * 256];
    __shared__ float payLDS[2];
    __shared__ float wtotLDS[2];
    __shared__ float wsum[2][2];

    const int tid  = threadIdx.x;
    const int path = tid >> 7;            // which of the 2 paths in this block
    const int n    = tid & 127;           // time index along the path
    const int bm   = blockIdx.x * 2 + path;
    const int p    = bm * N_ + n;         // flat point index

    // ---- loads (all per-lane; consecutive lanes -> consecutive addresses) ----
    float tval = tt[p];
    float xr[D_];
    {
        const float2* v = reinterpret_cast<const float2*>(xx + (size_t)p * D_);
        #pragma unroll
        for (int i = 0; i < 5; ++i) { float2 w = v[i]; xr[2*i] = w.x; xr[2*i+1] = w.y; }
    }
    float4 uv = *reinterpret_cast<const float4*>(uu + (size_t)p * K_);
    float dwr[D_];
    if (n < N_ - 1) {
        const float2* v = reinterpret_cast<const float2*>(dw + ((size_t)bm * (N_-1) + n) * D_);
        #pragma unroll
        for (int i = 0; i < 5; ++i) { float2 w = v[i]; dwr[2*i] = w.x; dwr[2*i+1] = w.y; }
    } else {
        #pragma unroll
        for (int i = 0; i < D_; ++i) dwr[i] = 0.f;
    }
    float r_ = uv.x, sigma = uv.y;
    float a[D_];
    #pragma unroll
    for (int d = 0; d < D_; ++d) a[d] = sigma * xr[d] * dwr[d];

    // payoff from the terminal point of each path
    if (n == N_ - 1) {
        float s = 0.f;
        #pragma unroll
        for (int d = 0; d < D_; ++d) s += xr[d];
        payLDS[path] = fmaxf(s * (1.f / D_) - STRIKE_, 0.f);
    }

    // ---- layer 1: acc[h] = b1[h] + z . W1[:,h]   (W1 rows are wave-uniform -> s_load) ----
    float acc[H_];
    #pragma unroll
    for (int h = 0; h < H_; ++h) acc[h] = b1[h];
    #pragma unroll
    for (int h = 0; h < H_; ++h) acc[h] = fmaf(tval, W1[h], acc[h]);
    #pragma unroll
    for (int i = 0; i < D_; ++i) {
        const float* w = W1 + (1 + i) * H_;
        float zi = xr[i];
        #pragma unroll
        for (int h = 0; h < H_; ++h) acc[h] = fmaf(zi, w[h], acc[h]);
    }
    {
        float ur[K_] = {uv.x, uv.y, uv.z, uv.w};
        #pragma unroll
        for (int i = 0; i < K_; ++i) {
            const float* w = W1 + (1 + D_ + i) * H_;
            #pragma unroll
            for (int h = 0; h < H_; ++h) acc[h] = fmaf(ur[i], w[h], acc[h]);
        }
    }

    // h1 -> LDS fp16 (own column; no barrier needed, same-thread readback only)
    #pragma unroll
    for (int h = 0; h < H_; ++h) A1[h * 256 + tid] = (_Float16)fast_tanh(acc[h]);

    // ---- layer 2: acc[h] = b2[h] + sum_i h1[i] * W2[i][h] ----
    #pragma unroll
    for (int h = 0; h < H_; ++h) acc[h] = b2[h];
    #pragma unroll 1
    for (int i = 0; i < H_; ++i) {
        float h1i = (float)A1[i * 256 + tid];
        const float* w = W2 + i * H_;
        #pragma unroll
        for (int h = 0; h < H_; ++h) acc[h] = fmaf(h1i, w[h], acc[h]);
    }

    // ---- epilogue: f = b3 + W3 . tanh(acc);  g2[h] = W3[h]*(1-h2^2) kept in acc ----
    float fp[8];
    #pragma unroll
    for (int j = 0; j < 8; ++j) fp[j] = 0.f;
    #pragma unroll
    for (int h = 0; h < H_; ++h) {
        float h2 = fast_tanh(acc[h]);
        float w3 = W3[h];
        fp[h & 7] = fmaf(w3, h2, fp[h & 7]);
        acc[h] = w3 * (1.f - h2 * h2);
    }
    float f = ((fp[0]+fp[4]) + (fp[1]+fp[5])) + ((fp[2]+fp[6]) + (fp[3]+fp[7]));
    f += b3[0];

    // ---- backward + z-term:  zterm = sum_i g1_i * q_i ----
    // g1_i = (W2[i][:] . g2) * (1 - h1_i^2),  q_i = sum_d a_d * W1T[i][d]
    float zt[4]; zt[0] = zt[1] = zt[2] = zt[3] = 0.f;
    #pragma unroll 1
    for (int i = 0; i < H_; ++i) {
        const float* w = W2 + i * H_;
        float pp[8];
        #pragma unroll
        for (int j = 0; j < 8; ++j) pp[j] = 0.f;
        #pragma unroll
        for (int h = 0; h < H_; ++h) pp[h & 7] = fmaf(w[h], acc[h], pp[h & 7]);
        float gpre = ((pp[0]+pp[4]) + (pp[1]+pp[5])) + ((pp[2]+pp[6]) + (pp[3]+pp[7]));
        float h1i = (float)A1[i * 256 + tid];
        float g1 = gpre * (1.f - h1i * h1i);
        const float* wt = W1T + i * 16;
        float q = 0.f;
        #pragma unroll
        for (int d = 0; d < D_; ++d) q = fmaf(a[d], wt[d], q);
        zt[i & 3] = fmaf(g1, q, zt[i & 3]);
    }
    float zterm = (zt[0] + zt[2]) + (zt[1] + zt[3]);

    // c[n] = r*f*DT - z  (0 at terminal)
    float cn = (n < N_ - 1) ? fmaf(r_ * f, DT_, -zterm) : 0.f;

    // ---- suffix scan S[n] = sum_{j>=n} c[j] over each path's 128 threads (2 waves) ----
    float S = cn;
    #pragma unroll
    for (int off = 1; off < 64; off <<= 1) {
        float o = __shfl_down(S, off);
        S += (((n & 63) + off) < 64) ? o : 0.f;
    }
    if (n == 64) wtotLDS[path] = S;    // total of the path's upper wave (n=64..127)
    __syncthreads();                   // also publishes payLDS
    if (n < 64) S += wtotLDS[path];
    float pay = payLDS[path];

    float resid = (n < N_ - 1) ? (pay - f + S) : 0.f;
    float v = resid * resid;
    #pragma unroll
    for (int off = 32; off; off >>= 1) v += __shfl_down(v, off);
    if ((n & 63) == 0) wsum[path][n >> 6] = v;
    __syncthreads();
    if (n == 0) atomicAdd(gI, wsum[path][0] + wsum[path][1]);
    if (n == N_ - 1) { float d0 = f - pay; atomicAdd(gT, d0 * d0); }
}

extern "C" __global__ void solver_fin(const float* gI, const float* gT, float* out) {
    float li = *gI * (1.f / (B_ * M_));
    float lt = *gT * (1.f / (B_ * M_));
    out[0] = 1.0f * lt + li;   // ALPHA = 1
    out[1] = li;
    out[2] = lt;
}

extern "C" void kernel_launch(void* const* d_in, const int* in_sizes, int n_in,
                              void* d_out, int out_size, void* d_ws, size_t ws_size,
                              hipStream_t stream) {
    const float* tt = (const float*)d_in[0];
    const float* xx = (const float*)d_in[1];
    const float* dw = (const float*)d_in[2];
    const float* uu = (const float*)d_in[3];
    const float* W1 = (const float*)d_in[4];
    const float* b1 = (const float*)d_in[5];
    const float* W2 = (const float*)d_in[6];
    const float* b2 = (const float*)d_in[7];
    const float* W3 = (const float*)d_in[8];
    const float* b3 = (const float*)d_in[9];
    float* out = (float*)d_out;
    float* ws  = (float*)d_ws;
    float* gI  = ws;          // [0] interior sum
    float* gT  = ws + 1;      // [1] terminal sum
    float* W1T = ws + 8;      // 64*16 floats, 32B-aligned

    hipLaunchKernelGGL(solver_setup, dim3(1), dim3(64), 0, stream, W1, W1T, gI, gT);
    hipLaunchKernelGGL(solver_main, dim3(B_ * M_ / 2), dim3(256), 0, stream,
                       tt, xx, dw, uu, W1, b1, W2, b2, W3, b3, W1T, gI, gT);
    hipLaunchKernelGGL(solver_fin, dim3(1), dim3(1), 0, stream, gI, gT, out);
}

// Round 11
// 467.866 us; speedup vs baseline: 1.1989x; 1.0721x over previous
//
#include <hip/hip_runtime.h>

#define B_ 128
#define M_ 64
#define N_ 128
#define D_ 10
#define K_ 4
#define H_ 64
#define DT_ (1.0f/128.0f)
#define STRIKE_ 0.4f

// tanh(x) = (1 - e^{-2x}) / (1 + e^{-2x});  e^{-2x} = exp2(-2*log2(e)*x)
__device__ __forceinline__ float fast_tanh(float x) {
    x = fminf(30.f, fmaxf(-30.f, x));
    float e = __builtin_amdgcn_exp2f(x * -2.885390081777927f);
    return (1.f - e) * __builtin_amdgcn_rcpf(1.f + e);
}

// Setup: zero accumulators, build W1T[h][d] = W1[(1+d)*H + h] (the 10 x-rows, padded to 16)
extern "C" __global__ void solver_setup(const float* __restrict__ W1,
                                        float* __restrict__ W1T,
                                        float* gI, float* gT) {
    int h = threadIdx.x;
    if (h == 0) { *gI = 0.f; *gT = 0.f; }
    #pragma unroll
    for (int d = 0; d < 16; ++d)
        W1T[h * 16 + d] = (d < D_) ? W1[(1 + d) * H_ + h] : 0.f;
}

// Merged fwd-L2 + bwd pass:
//   zterm = sum_i g1_i q_i = sum_h g2[h] * s[h],  s[h] = sum_i W2[i][h] * v_i,
//   v_i = (1-h1_i^2) q_i  (independent of g2!)
// -> each W2 row s_loaded ONCE (was twice); loop body has 128 independent fmas
//    (acc & s chains) vs 64 -> 2x ILP; per-row pp reduction tree eliminated.
// lb(256,2): VGPR cap 256, need ~160-180 (acc[64]+s[64]+a[10]+temps). No forced spill.
extern "C" __global__ void __launch_bounds__(256, 2)
solver_main(const float* __restrict__ tt, const float* __restrict__ xx,
            const float* __restrict__ dw, const float* __restrict__ uu,
            const float* __restrict__ W1, const float* __restrict__ b1,
            const float* __restrict__ W2, const float* __restrict__ b2,
            const float* __restrict__ W3, const float* __restrict__ b3,
            const float* __restrict__ W1T,
            float* __restrict__ gI, float* __restrict__ gT)
{
    // h1 transposed, fp16: A1[h*256 + tid]. Per-thread column only -> no barrier.
    __shared__ _Float16 A1[H_ * 256];
    __shared__ float payLDS[2];
    __shared__ float wtotLDS[2];
    __shared__ float wsum[2][2];

    const int tid  = threadIdx.x;
    const int path = tid >> 7;            // which of the 2 paths in this block
    const int n    = tid & 127;           // time index along the path
    const int bm   = blockIdx.x * 2 + path;
    const int p    = bm * N_ + n;         // flat point index

    // ---- loads (all per-lane; consecutive lanes -> consecutive addresses) ----
    float tval = tt[p];
    float xr[D_];
    {
        const float2* v = reinterpret_cast<const float2*>(xx + (size_t)p * D_);
        #pragma unroll
        for (int i = 0; i < 5; ++i) { float2 w = v[i]; xr[2*i] = w.x; xr[2*i+1] = w.y; }
    }
    float4 uv = *reinterpret_cast<const float4*>(uu + (size_t)p * K_);
    float dwr[D_];
    if (n < N_ - 1) {
        const float2* v = reinterpret_cast<const float2*>(dw + ((size_t)bm * (N_-1) + n) * D_);
        #pragma unroll
        for (int i = 0; i < 5; ++i) { float2 w = v[i]; dwr[2*i] = w.x; dwr[2*i+1] = w.y; }
    } else {
        #pragma unroll
        for (int i = 0; i < D_; ++i) dwr[i] = 0.f;
    }
    float r_ = uv.x, sigma = uv.y;
    float a[D_];
    #pragma unroll
    for (int d = 0; d < D_; ++d) a[d] = sigma * xr[d] * dwr[d];

    // payoff from the terminal point of each path
    if (n == N_ - 1) {
        float s0 = 0.f;
        #pragma unroll
        for (int d = 0; d < D_; ++d) s0 += xr[d];
        payLDS[path] = fmaxf(s0 * (1.f / D_) - STRIKE_, 0.f);
    }

    // ---- layer 1: acc[h] = b1[h] + z . W1[:,h]   (W1 rows are wave-uniform -> s_load) ----
    float acc[H_];
    #pragma unroll
    for (int h = 0; h < H_; ++h) acc[h] = b1[h];
    #pragma unroll
    for (int h = 0; h < H_; ++h) acc[h] = fmaf(tval, W1[h], acc[h]);
    #pragma unroll
    for (int i = 0; i < D_; ++i) {
        const float* w = W1 + (1 + i) * H_;
        float zi = xr[i];
        #pragma unroll
        for (int h = 0; h < H_; ++h) acc[h] = fmaf(zi, w[h], acc[h]);
    }
    {
        float ur[K_] = {uv.x, uv.y, uv.z, uv.w};
        #pragma unroll
        for (int i = 0; i < K_; ++i) {
            const float* w = W1 + (1 + D_ + i) * H_;
            #pragma unroll
            for (int h = 0; h < H_; ++h) acc[h] = fmaf(ur[i], w[h], acc[h]);
        }
    }

    // h1 -> LDS fp16 (own column; no barrier needed, same-thread readback only)
    #pragma unroll
    for (int h = 0; h < H_; ++h) A1[h * 256 + tid] = (_Float16)fast_tanh(acc[h]);

    // ---- merged layer 2 fwd + bwd-s pass ----
    // acc[h] = b2[h] + sum_i h1_i W2[i][h];  s[h] = sum_i v_i W2[i][h]
    float s[H_];
    #pragma unroll
    for (int h = 0; h < H_; ++h) { acc[h] = b2[h]; s[h] = 0.f; }
    #pragma unroll 1
    for (int i = 0; i < H_; ++i) {
        float h1i = (float)A1[i * 256 + tid];
        const float* w  = W2 + i * H_;
        const float* wt = W1T + i * 16;
        float q = 0.f;
        #pragma unroll
        for (int d = 0; d < D_; ++d) q = fmaf(a[d], wt[d], q);
        float v = (1.f - h1i * h1i) * q;
        #pragma unroll
        for (int h = 0; h < H_; ++h) {
            acc[h] = fmaf(h1i, w[h], acc[h]);
            s[h]   = fmaf(v,   w[h], s[h]);
        }
    }

    // ---- epilogue: f = b3 + W3.tanh(acc);  zterm = sum_h (W3[h](1-h2^2)) * s[h] ----
    float fp[4] = {0.f, 0.f, 0.f, 0.f};
    float zp[4] = {0.f, 0.f, 0.f, 0.f};
    #pragma unroll
    for (int h = 0; h < H_; ++h) {
        float h2 = fast_tanh(acc[h]);
        float w3 = W3[h];
        fp[h & 3] = fmaf(w3, h2, fp[h & 3]);
        float g2h = w3 * (1.f - h2 * h2);
        zp[h & 3] = fmaf(g2h, s[h], zp[h & 3]);
    }
    float f = (fp[0] + fp[2]) + (fp[1] + fp[3]) + b3[0];
    float zterm = (zp[0] + zp[2]) + (zp[1] + zp[3]);

    // c[n] = r*f*DT - z  (0 at terminal)
    float cn = (n < N_ - 1) ? fmaf(r_ * f, DT_, -zterm) : 0.f;

    // ---- suffix scan S[n] = sum_{j>=n} c[j] over each path's 128 threads (2 waves) ----
    float S = cn;
    #pragma unroll
    for (int off = 1; off < 64; off <<= 1) {
        float o = __shfl_down(S, off);
        S += (((n & 63) + off) < 64) ? o : 0.f;
    }
    if (n == 64) wtotLDS[path] = S;    // total of the path's upper wave (n=64..127)
    __syncthreads();                   // also publishes payLDS
    if (n < 64) S += wtotLDS[path];
    float pay = payLDS[path];

    float resid = (n < N_ - 1) ? (pay - f + S) : 0.f;
    float v2 = resid * resid;
    #pragma unroll
    for (int off = 32; off; off >>= 1) v2 += __shfl_down(v2, off);
    if ((n & 63) == 0) wsum[path][n >> 6] = v2;
    __syncthreads();
    if (n == 0) atomicAdd(gI, wsum[path][0] + wsum[path][1]);
    if (n == N_ - 1) { float d0 = f - pay; atomicAdd(gT, d0 * d0); }
}

extern "C" __global__ void solver_fin(const float* gI, const float* gT, float* out) {
    float li = *gI * (1.f / (B_ * M_));
    float lt = *gT * (1.f / (B_ * M_));
    out[0] = 1.0f * lt + li;   // ALPHA = 1
    out[1] = li;
    out[2] = lt;
}

extern "C" void kernel_launch(void* const* d_in, const int* in_sizes, int n_in,
                              void* d_out, int out_size, void* d_ws, size_t ws_size,
                              hipStream_t stream) {
    const float* tt = (const float*)d_in[0];
    const float* xx = (const float*)d_in[1];
    const float* dw = (const float*)d_in[2];
    const float* uu = (const float*)d_in[3];
    const float* W1 = (const float*)d_in[4];
    const float* b1 = (const float*)d_in[5];
    const float* W2 = (const float*)d_in[6];
    const float* b2 = (const float*)d_in[7];
    const float* W3 = (const float*)d_in[8];
    const float* b3 = (const float*)d_in[9];
    float* out = (float*)d_out;
    float* ws  = (float*)d_ws;
    float* gI  = ws;          // [0] interior sum
    float* gT  = ws + 1;      // [1] terminal sum
    float* W1T = ws + 8;      // 64*16 floats, 32B-aligned

    hipLaunchKernelGGL(solver_setup, dim3(1), dim3(64), 0, stream, W1, W1T, gI, gT);
    hipLaunchKernelGGL(solver_main, dim3(B_ * M_ / 2), dim3(256), 0, stream,
                       tt, xx, dw, uu, W1, b1, W2, b2, W3, b3, W1T, gI, gT);
    hipLaunchKernelGGL(solver_fin, dim3(1), dim3(1), 0, stream, gI, gT, out);
}